// Round 2
// 2099.901 us; speedup vs baseline: 1.1264x; 1.1264x over previous
//
#include <hip/hip_runtime.h>

#define NN 20000
#define EE 640000
#define H 256
#define H3 768

typedef __attribute__((ext_vector_type(8))) short bfrag;
typedef __attribute__((ext_vector_type(4))) float f32x4;
typedef __attribute__((ext_vector_type(2))) unsigned short u16x2;
typedef __attribute__((ext_vector_type(4))) unsigned short u16x4;
typedef unsigned short u16;

__device__ __forceinline__ float silu_f(float x){ return x / (1.f + __expf(-x)); }

__device__ __forceinline__ u16 f2bf(float f){
  union { float fv; unsigned u; } a; a.fv = f;
  unsigned r = a.u + 0x7fffu + ((a.u >> 16) & 1u);   // RNE
  return (u16)(r >> 16);
}
__device__ __forceinline__ float bf2f(u16 u){
  union { unsigned u32; float f; } a; a.u32 = ((unsigned)u) << 16; return a.f;
}

// ---------------- LayerNorm -> split bf16 (hi/lo) ----------------
__global__ __launch_bounds__(256) void ln_kernel(
    const float* __restrict__ x, const float* __restrict__ w,
    const float* __restrict__ b, u16* __restrict__ xnh, u16* __restrict__ xnl)
{
  int n = blockIdx.x, t = threadIdx.x;
  float v = x[(size_t)n*H + t];
  float s1 = v, s2 = v*v;
  #pragma unroll
  for(int o=32;o>0;o>>=1){ s1 += __shfl_down(s1,o,64); s2 += __shfl_down(s2,o,64); }
  __shared__ float r1[4], r2[4];
  if((t&63)==0){ r1[t>>6]=s1; r2[t>>6]=s2; }
  __syncthreads();
  float mu  = (r1[0]+r1[1]+r1[2]+r1[3]) * (1.f/256.f);
  float ex2 = (r2[0]+r2[1]+r2[2]+r2[3]) * (1.f/256.f);
  float inv = rsqrtf(ex2 - mu*mu + 1e-5f);
  float y = (v - mu)*inv*w[t] + b[t];
  u16 h = f2bf(y);
  xnh[(size_t)n*H + t] = h;
  xnl[(size_t)n*H + t] = f2bf(y - bf2f(h));
}

// ---- W [256, ldw] fp32 -> [ncols][256] n-major hi/lo bf16 (mode1: vec paired perm) ----
__global__ __launch_bounds__(256) void wconv(
    const float* __restrict__ W, int ldw,
    u16* __restrict__ oh, u16* __restrict__ ol, int mode)
{
  int idx = blockIdx.x*256 + threadIdx.x;   // grid.x = ncols
  int n = idx >> 8, k = idx & 255;
  int c = n;
  if(mode == 1){
    int y = n >> 7, j = n & 127;
    c = (j < 64) ? (y*64 + j) : (256 + y*64 + (j - 64));
  }
  float f = W[(size_t)k*ldw + c];
  u16 h = f2bf(f);
  oh[idx] = h;
  ol[idx] = f2bf(f - bf2f(h));
}

// ---- vec fp32 -> hi + lo residual ----
__global__ __launch_bounds__(256) void cvt_vec(
    const float* __restrict__ src, u16* __restrict__ hi, u16* __restrict__ lo, int n4)
{
  int i = blockIdx.x*256 + threadIdx.x;
  if(i < n4){
    float4 v = ((const float4*)src)[i];
    u16x4 oh, olo;
    float a[4] = {v.x, v.y, v.z, v.w};
    #pragma unroll
    for(int j=0;j<4;j++){
      u16 h = f2bf(a[j]);
      oh[j]  = h;
      olo[j] = f2bf(a[j] - bf2f(h));
    }
    ((u16x4*)hi)[i] = oh;
    ((u16x4*)lo)[i] = olo;
  }
}

// ---- generic split-bf16 MFMA GEMM: C[M,ldw] = A[M,256] @ W[256,ldw] + bias ----
// A given as hi/lo bf16 row-major [M][256]; W pre-transposed n-major hi/lo [ldw][256].
// OUT 0: fp32 to Cf; OUT 1: bf16 to Ch.
template<int OUT>
__global__ __launch_bounds__(256) void gemm_split(
    const u16* __restrict__ Ah, const u16* __restrict__ Al,
    const u16* __restrict__ Bh, const u16* __restrict__ Bl,
    const float* __restrict__ bias,
    float* __restrict__ Cf, u16* __restrict__ Ch, int ldw, int M)
{
  int tid  = threadIdx.x;
  int wid  = tid >> 6, lane = tid & 63;
  int ln15 = lane & 15, quad = lane >> 4;
  int wr = wid >> 1, wc = wid & 1;
  int m0 = blockIdx.x*128 + wr*64;
  int n0 = blockIdx.y*128 + wc*64;

  int arow[4];
  #pragma unroll
  for(int mi=0;mi<4;mi++){
    int r = m0 + mi*16 + ln15;
    arow[mi] = (r < M) ? r : (M-1);
  }
  int ncol[4];
  #pragma unroll
  for(int ni=0;ni<4;ni++) ncol[ni] = n0 + ni*16 + ln15;

  f32x4 acc[4][4] = {};

  #pragma unroll 2
  for(int ks=0; ks<8; ks++){
    int kb = ks*32 + quad*8;
    bfrag ah[4], al[4], bh[4], bl[4];
    #pragma unroll
    for(int mi=0;mi<4;mi++){
      ah[mi] = *(const bfrag*)(Ah + ((size_t)arow[mi] << 8) + kb);
      al[mi] = *(const bfrag*)(Al + ((size_t)arow[mi] << 8) + kb);
    }
    #pragma unroll
    for(int ni=0;ni<4;ni++){
      bh[ni] = *(const bfrag*)(Bh + ((size_t)ncol[ni] << 8) + kb);
      bl[ni] = *(const bfrag*)(Bl + ((size_t)ncol[ni] << 8) + kb);
    }
    #pragma unroll
    for(int mi=0;mi<4;mi++)
      #pragma unroll
      for(int ni=0;ni<4;ni++){
        acc[mi][ni] = __builtin_amdgcn_mfma_f32_16x16x32_bf16(ah[mi], bh[ni], acc[mi][ni], 0,0,0);
        acc[mi][ni] = __builtin_amdgcn_mfma_f32_16x16x32_bf16(ah[mi], bl[ni], acc[mi][ni], 0,0,0);
        acc[mi][ni] = __builtin_amdgcn_mfma_f32_16x16x32_bf16(al[mi], bh[ni], acc[mi][ni], 0,0,0);
      }
  }

  #pragma unroll
  for(int mi=0;mi<4;mi++){
    #pragma unroll
    for(int ni=0;ni<4;ni++){
      int col = ncol[ni];
      float bs = bias ? bias[col] : 0.f;
      #pragma unroll
      for(int r=0;r<4;r++){
        int row = m0 + mi*16 + quad*4 + r;
        if(row < M){
          float v = acc[mi][ni][r] + bs;
          if(OUT == 0) Cf[(size_t)row*ldw + col] = v;
          else         Ch[(size_t)row*ldw + col] = f2bf(v);
        }
      }
    }
  }
}

// ---- fused vec_proj(vec1,vec2) + vec_dot: writes vd[N,256] directly ----
// A = vec hi/lo [60000][256]; Bp = paired-permuted Wvec cols hi/lo [512][256].
// Block: BM=96 rows (=32 nodes), wc=0 waves compute vec1 cols, wc=1 the matched vec2 cols.
__global__ __launch_bounds__(256) void gemm_vecdot(
    const u16* __restrict__ Ah, const u16* __restrict__ Al,
    const u16* __restrict__ Bh, const u16* __restrict__ Bl,
    float* __restrict__ vd)
{
  __shared__ float l1[96][66];
  __shared__ float l2[96][66];
  int tid  = threadIdx.x;
  int wid  = tid >> 6, lane = tid & 63;
  int ln15 = lane & 15, quad = lane >> 4;
  int wr = wid >> 1, wc = wid & 1;
  int m0 = blockIdx.x*96;
  int y  = blockIdx.y;       // 0..3 -> vd cols [y*64, y*64+64)
  int rowb = wr*48;

  int arow[3];
  #pragma unroll
  for(int mi=0;mi<3;mi++) arow[mi] = m0 + rowb + mi*16 + ln15;   // exact: 625*96 = 60000
  int ncol[4];
  #pragma unroll
  for(int ni=0;ni<4;ni++) ncol[ni] = y*128 + wc*64 + ni*16 + ln15;

  f32x4 acc[3][4] = {};

  #pragma unroll 2
  for(int ks=0; ks<8; ks++){
    int kb = ks*32 + quad*8;
    bfrag ah[3], al[3], bh[4], bl[4];
    #pragma unroll
    for(int mi=0;mi<3;mi++){
      ah[mi] = *(const bfrag*)(Ah + ((size_t)arow[mi] << 8) + kb);
      al[mi] = *(const bfrag*)(Al + ((size_t)arow[mi] << 8) + kb);
    }
    #pragma unroll
    for(int ni=0;ni<4;ni++){
      bh[ni] = *(const bfrag*)(Bh + ((size_t)ncol[ni] << 8) + kb);
      bl[ni] = *(const bfrag*)(Bl + ((size_t)ncol[ni] << 8) + kb);
    }
    #pragma unroll
    for(int mi=0;mi<3;mi++)
      #pragma unroll
      for(int ni=0;ni<4;ni++){
        acc[mi][ni] = __builtin_amdgcn_mfma_f32_16x16x32_bf16(ah[mi], bh[ni], acc[mi][ni], 0,0,0);
        acc[mi][ni] = __builtin_amdgcn_mfma_f32_16x16x32_bf16(ah[mi], bl[ni], acc[mi][ni], 0,0,0);
        acc[mi][ni] = __builtin_amdgcn_mfma_f32_16x16x32_bf16(al[mi], bh[ni], acc[mi][ni], 0,0,0);
      }
  }

  // stage both halves
  #pragma unroll
  for(int mi=0;mi<3;mi++)
    #pragma unroll
    for(int ni=0;ni<4;ni++)
      #pragma unroll
      for(int r=0;r<4;r++){
        int lr = rowb + mi*16 + quad*4 + r;
        int lc = ni*16 + ln15;
        if(wc == 0) l1[lr][lc] = acc[mi][ni][r];
        else        l2[lr][lc] = acc[mi][ni][r];
      }
  __syncthreads();

  // d-sum of pair products -> vd
  #pragma unroll
  for(int i=0;i<8;i++){
    int id  = i*256 + tid;       // 2048 = 32 nodes x 64 cols
    int n_l = id >> 6, c = id & 63;
    float s = 0.f;
    #pragma unroll
    for(int d=0;d<3;d++) s += l1[n_l*3+d][c] * l2[n_l*3+d][c];
    vd[((size_t)(blockIdx.x*32 + n_l) << 8) + y*64 + c] = s;
  }
}

// ---------------- CSR build ----------------
__global__ __launch_bounds__(256) void hist_kernel(const int* __restrict__ ei, int* __restrict__ deg){
  int e = blockIdx.x*256 + threadIdx.x;
  if(e < EE) atomicAdd(&deg[ei[EE + e]], 1);
}

__global__ __launch_bounds__(1024) void scan_kernel(const int* __restrict__ deg, int* __restrict__ offs){
  __shared__ int ps[1024];
  int t = threadIdx.x;
  int base = t*20;
  int s = 0;
  for(int i=0;i<20;i++){ int idx = base+i; if(idx < NN) s += deg[idx]; }
  ps[t] = s; __syncthreads();
  for(int off=1; off<1024; off<<=1){
    int v = (t>=off) ? ps[t-off] : 0;
    __syncthreads();
    ps[t] += v;
    __syncthreads();
  }
  int run = (t==0) ? 0 : ps[t-1];
  for(int i=0;i<20;i++){
    int idx = base+i;
    if(idx <= NN){
      offs[idx] = run;
      if(idx < NN) run += deg[idx];
    }
  }
}

__global__ __launch_bounds__(256) void scatter_kernel(
    const int* __restrict__ ei, const int* __restrict__ offs,
    int* __restrict__ cursor, int* __restrict__ perm)
{
  int e = blockIdx.x*256 + threadIdx.x;
  if(e >= EE) return;
  int d = ei[EE + e];
  int r = atomicAdd(&cursor[d], 1);
  perm[offs[d] + r] = e;
}

// ---------------- weight -> bf16 B-fragment layout (channel-interleaved) ----------------
__global__ __launch_bounds__(256) void conv_wdk(const float* __restrict__ Wdk, short* __restrict__ wdkf){
  int idx = blockIdx.x*256 + threadIdx.x;      // 64*256
  int k = idx >> 8, c = idx & 255;
  int g = c >> 6, rem = c & 63, n15 = rem >> 2, p = rem & 3;
  int half = k >> 5, quad = (k >> 3) & 3, j = k & 7;
  wdkf[(g*4+p)*1024 + half*512 + quad*128 + n15*8 + j] = (short)f2bf(Wdk[k*H + c]);
}

__global__ __launch_bounds__(256) void conv_wdv(const float* __restrict__ Wdv, short* __restrict__ wdvf){
  int idx = blockIdx.x*256 + threadIdx.x;      // 64*768
  int k = idx / 768, c = idx % 768;
  int h = c / 96, jj = c % 96;
  int st = jj >> 5, r32 = jj & 31, n15 = r32 >> 1, p = r32 & 1;
  int sub = h*6 + st*2 + p;
  int half = k >> 5, quad = (k >> 3) & 3, j = k & 7;
  wdvf[sub*1024 + half*512 + quad*128 + n15*8 + j] = (short)f2bf(Wdv[k*H3 + c]);
}

// ---------------- edge kernel: one wave per dst node, bf16 vectorized gathers ----------------
__global__ __launch_bounds__(256,3) void edge_kernel(
    const int* __restrict__ ei, const float* __restrict__ rij,
    const float* __restrict__ fij, const float* __restrict__ dij,
    const float* __restrict__ qg, const u16* __restrict__ kh,
    const u16* __restrict__ vh, const u16* __restrict__ vech,
    const short* __restrict__ wdkf, const short* __restrict__ wdvf,
    const float* __restrict__ bdk, const float* __restrict__ bdv,
    const int* __restrict__ offs, const int* __restrict__ perm,
    u16* __restrict__ xaggh, u16* __restrict__ xaggl, float* __restrict__ dvec)
{
  __shared__ float accs_x[4][256];
  __shared__ float accs_v[4][768];
  __shared__ float attn_s[4][16][8];
  __shared__ int   esrc_s[4][16];
  __shared__ float ecut_s[4][16];
  __shared__ float emask_s[4][16];
  __shared__ float edij_s[4][3][16];

  int tid  = threadIdx.x;
  int wv   = tid >> 6, lane = tid & 63;
  int ln15 = lane & 15, quad = lane >> 4;
  int n    = blockIdx.x*4 + wv;
  int rs = offs[n], re = offs[n+1];

  #pragma unroll
  for(int i=0;i<4;i++)  accs_x[wv][i*64 + lane] = 0.f;
  #pragma unroll
  for(int i=0;i<12;i++) accs_v[wv][i*64 + lane] = 0.f;

  float qreg[16], bkreg[16];
  #pragma unroll
  for(int g=0; g<4; g++){
    float4 t = *(const float4*)(qg + (size_t)n*H + g*64 + 4*ln15);
    qreg[g*4+0]=t.x; qreg[g*4+1]=t.y; qreg[g*4+2]=t.z; qreg[g*4+3]=t.w;
    float4 u = *(const float4*)(bdk + g*64 + 4*ln15);
    bkreg[g*4+0]=u.x; bkreg[g*4+1]=u.y; bkreg[g*4+2]=u.z; bkreg[g*4+3]=u.w;
  }

  for(int base = rs; base < re; base += 16){
    int idx = base + ln15;
    bool val = idx < re;
    int e = perm[val ? idx : rs];
    if(quad == 0){
      esrc_s[wv][ln15] = ei[e];
      float r = rij[e];
      float cu = 0.5f*(__cosf(r*0.6283185307f)+1.f);
      cu = (r < 5.f) ? cu : 0.f;
      ecut_s[wv][ln15]  = val ? cu : 0.f;
      emask_s[wv][ln15] = val ? 1.f : 0.f;
      edij_s[wv][0][ln15] = dij[e*3+0];
      edij_s[wv][1][ln15] = dij[e*3+1];
      edij_s[wv][2][ln15] = dij[e*3+2];
    }
    bfrag af0, af1;
    {
      const float* fr = fij + (size_t)e*64 + quad*8;
      float4 fa = *(const float4*)fr;
      float4 fb = *(const float4*)(fr+4);
      float4 fc = *(const float4*)(fr+32);
      float4 fd = *(const float4*)(fr+36);
      af0[0]=(short)f2bf(fa.x); af0[1]=(short)f2bf(fa.y); af0[2]=(short)f2bf(fa.z); af0[3]=(short)f2bf(fa.w);
      af0[4]=(short)f2bf(fb.x); af0[5]=(short)f2bf(fb.y); af0[6]=(short)f2bf(fb.z); af0[7]=(short)f2bf(fb.w);
      af1[0]=(short)f2bf(fc.x); af1[1]=(short)f2bf(fc.y); af1[2]=(short)f2bf(fc.z); af1[3]=(short)f2bf(fc.w);
      af1[4]=(short)f2bf(fd.x); af1[5]=(short)f2bf(fd.y); af1[6]=(short)f2bf(fd.z); af1[7]=(short)f2bf(fd.w);
    }
    int sns[4]; float mk[4];
    #pragma unroll
    for(int r=0;r<4;r++){
      int el = quad*4 + r;
      sns[r] = esrc_s[wv][el];
      mk[r]  = emask_s[wv][el];
    }

    u16x4 kr[4][4];
    #pragma unroll
    for(int g=0;g<4;g++)
      #pragma unroll
      for(int r=0;r<4;r++)
        kr[g][r] = *(const u16x4*)(kh + (size_t)sns[r]*H + g*64 + 4*ln15);

    #pragma unroll
    for(int g=0;g<4;g++){
      float lgg[4] = {0.f,0.f,0.f,0.f};
      #pragma unroll
      for(int p=0;p<4;p++){
        const short* wp = wdkf + (g*4+p)*1024 + quad*128 + ln15*8;
        bfrag b0 = *(const bfrag*)wp;
        bfrag b1 = *(const bfrag*)(wp + 512);
        f32x4 acc = {0.f,0.f,0.f,0.f};
        acc = __builtin_amdgcn_mfma_f32_16x16x32_bf16(af0, b0, acc, 0,0,0);
        acc = __builtin_amdgcn_mfma_f32_16x16x32_bf16(af1, b1, acc, 0,0,0);
        float bias = bkreg[g*4+p], qv = qreg[g*4+p];
        #pragma unroll
        for(int r=0;r<4;r++){
          float dk = silu_f(acc[r] + bias);
          lgg[r] += dk * qv * bf2f(kr[g][r][p]);
        }
      }
      #pragma unroll
      for(int r=0;r<4;r++){
        lgg[r] += __shfl_xor(lgg[r],1,64);
        lgg[r] += __shfl_xor(lgg[r],2,64);
        lgg[r] += __shfl_xor(lgg[r],4,64);
      }
      if((ln15 & 7) == 0){
        int hh = 2*g + (ln15 >> 3);
        #pragma unroll
        for(int r=0;r<4;r++){
          int el = quad*4 + r;
          attn_s[wv][el][hh] = silu_f(lgg[r]) * ecut_s[wv][el];
        }
      }
    }

    #pragma unroll 1
    for(int h=0;h<8;h++){
      u16x2 vld[3][4], vcl[3][4];
      #pragma unroll
      for(int st=0;st<3;st++)
        #pragma unroll
        for(int r=0;r<4;r++)
          vld[st][r] = *(const u16x2*)(vh + (size_t)sns[r]*H3 + h*96 + st*32 + 2*ln15);
      #pragma unroll
      for(int d=0;d<3;d++)
        #pragma unroll
        for(int r=0;r<4;r++)
          vcl[d][r] = *(const u16x2*)(vech + (size_t)sns[r]*H3 + d*H + h*32 + 2*ln15);
      float bb[6];
      #pragma unroll
      for(int st=0;st<3;st++){
        float2 b2 = *(const float2*)(bdv + h*96 + st*32 + 2*ln15);
        bb[st*2] = b2.x; bb[st*2+1] = b2.y;
      }
      float at[4];
      #pragma unroll
      for(int r=0;r<4;r++) at[r] = attn_s[wv][quad*4+r][h];

      float v1v[2][4], vjv[2][4];
      float xmt[2] = {0.f, 0.f};
      #pragma unroll
      for(int st=0;st<3;st++){
        #pragma unroll
        for(int p=0;p<2;p++){
          const short* wp = wdvf + (h*6+st*2+p)*1024 + quad*128 + ln15*8;
          bfrag b0 = *(const bfrag*)wp;
          bfrag b1 = *(const bfrag*)(wp + 512);
          f32x4 acc = {0.f,0.f,0.f,0.f};
          acc = __builtin_amdgcn_mfma_f32_16x16x32_bf16(af0, b0, acc, 0,0,0);
          acc = __builtin_amdgcn_mfma_f32_16x16x32_bf16(af1, b1, acc, 0,0,0);
          float bias = bb[st*2+p];
          #pragma unroll
          for(int r=0;r<4;r++){
            float dvv = silu_f(acc[r] + bias) * mk[r];
            float vj = bf2f(vld[st][r][p]) * dvv;
            if(st == 0)      xmt[p]    += vj * at[r];
            else if(st == 1) v1v[p][r]  = vj;
            else             vjv[p][r]  = vj;
          }
        }
      }
      #pragma unroll
      for(int p=0;p<2;p++){
        xmt[p] += __shfl_xor(xmt[p],16,64);
        xmt[p] += __shfl_xor(xmt[p],32,64);
      }
      if(quad == 0){
        accs_x[wv][h*32 + 2*ln15 + 0] += xmt[0];
        accs_x[wv][h*32 + 2*ln15 + 1] += xmt[1];
      }
      #pragma unroll
      for(int d=0;d<3;d++){
        float t0 = 0.f, t1 = 0.f;
        #pragma unroll
        for(int r=0;r<4;r++){
          float dj = edij_s[wv][d][quad*4+r];
          t0 += bf2f(vcl[d][r][0]) * v1v[0][r] + dj * vjv[0][r];
          t1 += bf2f(vcl[d][r][1]) * v1v[1][r] + dj * vjv[1][r];
        }
        t0 += __shfl_xor(t0,16,64); t0 += __shfl_xor(t0,32,64);
        t1 += __shfl_xor(t1,16,64); t1 += __shfl_xor(t1,32,64);
        if(quad == 0){
          accs_v[wv][d*H + h*32 + 2*ln15 + 0] += t0;
          accs_v[wv][d*H + h*32 + 2*ln15 + 1] += t1;
        }
      }
    }
  }

  #pragma unroll
  for(int j=0;j<4;j++){
    float v = accs_x[wv][j*64 + lane];
    u16 h = f2bf(v);
    xaggh[(size_t)n*H + j*64 + lane] = h;
    xaggl[(size_t)n*H + j*64 + lane] = f2bf(v - bf2f(h));
  }
  #pragma unroll
  for(int j=0;j<12;j++) dvec[(size_t)n*H3 + j*64 + lane] = accs_v[wv][j*64 + lane];
}

// ---- epilogue ----
__global__ __launch_bounds__(256) void final_kernel(
    const float* __restrict__ ob, const float* __restrict__ vd,
    const float* __restrict__ vp3, float* __restrict__ out)
{
  int i = blockIdx.x*256 + threadIdx.x;
  int n = i >> 8, c = i & 255;
  float o1 = ob[(size_t)n*H3 + c];
  float o2 = ob[(size_t)n*H3 + 256 + c];
  float o3 = ob[(size_t)n*H3 + 512 + c];
  out[i] = vd[i]*o2 + o3;
  float* dvec = out + (size_t)NN*H;
  #pragma unroll
  for(int d=0;d<3;d++){
    dvec[(size_t)n*H3 + d*H + c] += vp3[(size_t)(3*n+d)*256 + c] * o1;
  }
}

extern "C" void kernel_launch(void* const* d_in, const int* in_sizes, int n_in,
                              void* d_out, int out_size, void* d_ws, size_t ws_size,
                              hipStream_t stream){
  (void)in_sizes; (void)n_in; (void)out_size; (void)ws_size;
  const float* x    = (const float*)d_in[0];
  const float* vec  = (const float*)d_in[1];
  const int*   ei   = (const int*)d_in[2];
  const float* rij  = (const float*)d_in[3];
  const float* fij  = (const float*)d_in[4];
  const float* dij  = (const float*)d_in[5];
  const float* ln_w = (const float*)d_in[6];
  const float* ln_b = (const float*)d_in[7];
  const float* Wq   = (const float*)d_in[8];
  const float* bq   = (const float*)d_in[9];
  const float* Wk   = (const float*)d_in[10];
  const float* bk   = (const float*)d_in[11];
  const float* Wv   = (const float*)d_in[12];
  const float* bv   = (const float*)d_in[13];
  const float* Wo   = (const float*)d_in[14];
  const float* bo   = (const float*)d_in[15];
  const float* Wvec = (const float*)d_in[16];
  const float* Wdk  = (const float*)d_in[17];
  const float* bdk  = (const float*)d_in[18];
  const float* Wdv  = (const float*)d_in[19];
  const float* bdv  = (const float*)d_in[20];
  float* out = (float*)d_out;
  float* ws  = (float*)d_ws;

  // workspace layout (float offsets), total ~313.1 MB
  float* vd    = ws;                       // [N,256] f32
  float* ob    = ws +  5120000;            // [N,768] f32 (after edge)
  float* vp3   = ws + 20480000;            // [3N,256] f32
  float* qb    = ws + 35840000;            // [N,256] f32
  u16*   kh    = (u16*)(ws + 40960000);    // [N,256] bf16
  u16*   vh    = (u16*)(ws + 43520000);    // [N,768] bf16
  u16*   vech  = (u16*)(ws + 51200000);    // [3N,256] bf16 (vec hi)
  u16*   vecl  = (u16*)(ws + 58880000);    // [3N,256] bf16 (vec lo)
  u16*   xnh   = (u16*)(ws + 66560000);    // [N,256]
  u16*   xnl   = (u16*)(ws + 69120000);
  u16*   xaggh = (u16*)(ws + 71680000);    // [N,256]
  u16*   xaggl = (u16*)(ws + 74240000);
  u16*   wt    = (u16*)(ws + 76800000);    // 1,441,792 u16 of transposed weights
  int*   deg    = (int*)(ws + 77530000);
  int*   offs   = deg + 20032;
  int*   cursor = offs + 20032;
  int*   perm   = cursor + 20032;          // 640000
  short* wdkf   = (short*)(perm + 640000);
  short* wdvf   = wdkf + 16384;

  u16* wtq_h = wt;            u16* wtq_l = wt +   65536;
  u16* wtk_h = wt +  131072;  u16* wtk_l = wt +  196608;
  u16* wtv_h = wt +  262144;  u16* wtv_l = wt +  458752;
  u16* wto_h = wt +  655360;  u16* wto_l = wt +  851968;
  u16* wtp_h = wt + 1048576;  u16* wtp_l = wt + 1179648;
  u16* wt3_h = wt + 1310720;  u16* wt3_l = wt + 1376256;

  float* dvec = out + (size_t)NN*H;

  ln_kernel<<<20000, 256, 0, stream>>>(x, ln_w, ln_b, xnh, xnl);

  wconv<<<256, 256, 0, stream>>>(Wq,        256, wtq_h, wtq_l, 0);
  wconv<<<256, 256, 0, stream>>>(Wk,        256, wtk_h, wtk_l, 0);
  wconv<<<768, 256, 0, stream>>>(Wv,        768, wtv_h, wtv_l, 0);
  wconv<<<768, 256, 0, stream>>>(Wo,        768, wto_h, wto_l, 0);
  wconv<<<512, 256, 0, stream>>>(Wvec,      768, wtp_h, wtp_l, 1);
  wconv<<<256, 256, 0, stream>>>(Wvec + 512,768, wt3_h, wt3_l, 0);

  gemm_split<0><<<dim3(157,2), 256, 0, stream>>>(xnh, xnl, wtq_h, wtq_l, bq, qb, nullptr, 256, 20000);
  gemm_split<1><<<dim3(157,2), 256, 0, stream>>>(xnh, xnl, wtk_h, wtk_l, bk, nullptr, kh, 256, 20000);
  gemm_split<1><<<dim3(157,6), 256, 0, stream>>>(xnh, xnl, wtv_h, wtv_l, bv, nullptr, vh, 768, 20000);

  cvt_vec<<<15000, 256, 0, stream>>>(vec, vech, vecl, 3840000);
  gemm_vecdot<<<dim3(625,4), 256, 0, stream>>>(vech, vecl, wtp_h, wtp_l, vd);
  gemm_split<0><<<dim3(469,2), 256, 0, stream>>>(vech, vecl, wt3_h, wt3_l, nullptr, vp3, nullptr, 256, 60000);

  hipMemsetAsync(deg,    0, 20000*sizeof(int), stream);
  hipMemsetAsync(cursor, 0, 20000*sizeof(int), stream);
  hist_kernel<<<2500, 256, 0, stream>>>(ei, deg);
  scan_kernel<<<1, 1024, 0, stream>>>(deg, offs);
  scatter_kernel<<<2500, 256, 0, stream>>>(ei, offs, cursor, perm);
  conv_wdk<<<64,  256, 0, stream>>>(Wdk, wdkf);
  conv_wdv<<<192, 256, 0, stream>>>(Wdv, wdvf);

  edge_kernel<<<5000, 256, 0, stream>>>(ei, rij, fij, dij, qb, kh, vh, vech,
                                        wdkf, wdvf, bdk, bdv, offs, perm,
                                        xaggh, xaggl, dvec);

  gemm_split<0><<<dim3(157,6), 256, 0, stream>>>(xaggh, xaggl, wto_h, wto_l, bo, ob, nullptr, 768, 20000);
  final_kernel<<<20000, 256, 0, stream>>>(ob, vd, vp3, out);
}